// Round 1
// baseline (836.944 us; speedup 1.0000x reference)
//
#include <hip/hip_runtime.h>

#define D 64

static __device__ __forceinline__ float bcast_lane(float x, int k) {
    return __int_as_float(__builtin_amdgcn_readlane(__float_as_int(x), k));
}

__global__ void zero_ints(int* __restrict__ p, int n) {
    int i = blockIdx.x * blockDim.x + threadIdx.x;
    if (i < n) p[i] = 0;
}

__global__ void count_deg(const int* __restrict__ dst, int E, int* __restrict__ counts) {
    int e = blockIdx.x * blockDim.x + threadIdx.x;
    if (e < E) atomicAdd(&counts[dst[e]], 1);
}

__global__ void compute_dis(const int* __restrict__ counts, float* __restrict__ dis, int N) {
    int i = blockIdx.x * blockDim.x + threadIdx.x;
    if (i < N) dis[i] = rsqrtf((float)(counts[i] + 1));  // +1 self-loop
}

// Single-block exclusive scan of counts[0..N) -> row_ptr[0..N]
__global__ void scan_rowptr(const int* __restrict__ counts, int* __restrict__ row_ptr, int N) {
    __shared__ int part[1024];
    int t = threadIdx.x;
    int chunk = (N + 1023) / 1024;
    int b0 = t * chunk;
    int b1 = min(b0 + chunk, N);
    int s = 0;
    for (int i = b0; i < b1; i++) s += counts[i];
    part[t] = s;
    __syncthreads();
    // Hillis-Steele inclusive scan
    for (int off = 1; off < 1024; off <<= 1) {
        int v = (t >= off) ? part[t - off] : 0;
        __syncthreads();
        part[t] += v;
        __syncthreads();
    }
    int run = (t == 0) ? 0 : part[t - 1];
    for (int i = b0; i < b1; i++) { row_ptr[i] = run; run += counts[i]; }
    if (t == 1023) row_ptr[N] = part[1023];
}

__global__ void fill_adj(const int* __restrict__ src, const int* __restrict__ dst, int E,
                         const float* __restrict__ dis, const int* __restrict__ row_ptr,
                         int* __restrict__ cursor, int* __restrict__ adj_src,
                         float* __restrict__ adj_norm) {
    int e = blockIdx.x * blockDim.x + threadIdx.x;
    if (e < E) {
        int s = src[e], d = dst[e];
        int pos = atomicAdd(&cursor[d], 1);
        int idx = row_ptr[d] + pos;
        adj_src[idx] = s;
        adj_norm[idx] = dis[s] * dis[d];
    }
}

// out[n][d] = sum_k in[n][k] * W[k][d]  (no bias; bias fused in aggregate)
// Wave-per-node; each lane d keeps W[:,d] (64 floats) in VGPRs; x-row broadcast
// via v_readlane. Zero LDS traffic.
__global__ __launch_bounds__(256) void gemm64(const float* __restrict__ in,
                                              const float* __restrict__ Wg,
                                              float* __restrict__ out, int N, int total_waves) {
    int lane = threadIdx.x & 63;
    int wave = (blockIdx.x * blockDim.x + threadIdx.x) >> 6;
    float w[D];
#pragma unroll
    for (int k = 0; k < D; k++) w[k] = Wg[k * D + lane];
    for (int n = wave; n < N; n += total_waves) {
        float xr = in[n * D + lane];
        float acc = 0.f;
#pragma unroll
        for (int k = 0; k < D; k++) acc += bcast_lane(xr, k) * w[k];
        out[n * D + lane] = acc;
    }
}

// Wave-per-node CSR gather + self-loop + bias + relu. No atomics.
__global__ __launch_bounds__(256) void aggregate(const float* __restrict__ h,
                                                 const int* __restrict__ row_ptr,
                                                 const int* __restrict__ adj_src,
                                                 const float* __restrict__ adj_norm,
                                                 const float* __restrict__ dis,
                                                 const float* __restrict__ bias,
                                                 float* __restrict__ out, int N) {
    int lane = threadIdx.x & 63;
    int wave = (blockIdx.x * blockDim.x + threadIdx.x) >> 6;
    if (wave >= N) return;
    int n = wave;
    float dn = dis[n];
    float acc = dn * dn * h[n * D + lane];
    int e = row_ptr[n];
    int e_end = row_ptr[n + 1];
    // 4-wide manual unroll so multiple 256B row-loads are in flight
    for (; e + 4 <= e_end; e += 4) {
        int a0 = adj_src[e], a1 = adj_src[e + 1], a2 = adj_src[e + 2], a3 = adj_src[e + 3];
        float w0 = adj_norm[e], w1 = adj_norm[e + 1], w2 = adj_norm[e + 2], w3 = adj_norm[e + 3];
        float r0 = h[a0 * D + lane];
        float r1 = h[a1 * D + lane];
        float r2 = h[a2 * D + lane];
        float r3 = h[a3 * D + lane];
        acc += w0 * r0;
        acc += w1 * r1;
        acc += w2 * r2;
        acc += w3 * r3;
    }
    for (; e < e_end; e++) acc += adj_norm[e] * h[adj_src[e] * D + lane];
    float v = acc + bias[lane];
    out[n * D + lane] = fmaxf(v, 0.f);
}

// One block per graph: binary-search segment bounds in sorted batch,
// register-accumulate pooled row, fuse final linear. No atomics.
__global__ __launch_bounds__(256) void pool_final(const float* __restrict__ h,
                                                  const int* __restrict__ batch, int N,
                                                  const float* __restrict__ lin_w,
                                                  const float* __restrict__ lin_b,
                                                  float* __restrict__ out) {
    int g = blockIdx.x;
    int lane = threadIdx.x & 63;
    int wv = threadIdx.x >> 6;

    int lo = 0, hi = N;
    while (lo < hi) { int mid = (lo + hi) >> 1; if (batch[mid] < g) lo = mid + 1; else hi = mid; }
    int start = lo;
    lo = 0; hi = N;
    while (lo < hi) { int mid = (lo + hi) >> 1; if (batch[mid] < g + 1) lo = mid + 1; else hi = mid; }
    int end = lo;

    float acc = 0.f;
    for (int n = start + wv; n < end; n += 4) acc += h[n * D + lane];

    __shared__ float red[4][D];
    red[wv][lane] = acc;
    __syncthreads();
    if (wv == 0) {
        float t = red[0][lane] + red[1][lane] + red[2][lane] + red[3][lane];
        t *= lin_w[lane];
#pragma unroll
        for (int off = 32; off >= 1; off >>= 1) t += __shfl_down(t, off, 64);
        if (lane == 0) out[g] = t + lin_b[0];
    }
}

extern "C" void kernel_launch(void* const* d_in, const int* in_sizes, int n_in,
                              void* d_out, int out_size, void* d_ws, size_t ws_size,
                              hipStream_t stream) {
    const float* x      = (const float*)d_in[0];
    const int*   edges  = (const int*)d_in[1];
    const int*   batch  = (const int*)d_in[2];
    const float* W1     = (const float*)d_in[3];
    const float* b1     = (const float*)d_in[4];
    const float* W2     = (const float*)d_in[5];
    const float* b2     = (const float*)d_in[6];
    const float* W3     = (const float*)d_in[7];
    const float* b3     = (const float*)d_in[8];
    const float* lin_w  = (const float*)d_in[9];
    const float* lin_b  = (const float*)d_in[10];
    float* out = (float*)d_out;

    const int N = in_sizes[2];        // 100000
    const int E = in_sizes[1] / 2;    // 1600000
    const int G = out_size;           // 64 graphs

    const int* e_src = edges;         // edge_index[0]
    const int* e_dst = edges + E;     // edge_index[1]

    // workspace layout (element offsets, 4B elems), 64-elem aligned
    auto al = [](long v) { return (v + 63) & ~63L; };
    long o_counts = 0;
    long o_cursor = al(o_counts + N);
    long o_rowptr = al(o_cursor + N);
    long o_dis    = al(o_rowptr + N + 1);
    long o_adjs   = al(o_dis + N);
    long o_adjn   = al(o_adjs + E);
    long o_hA     = al(o_adjn + E);
    long o_hB     = o_hA + (long)N * D;

    int*   counts  = (int*)d_ws + o_counts;
    int*   cursor  = (int*)d_ws + o_cursor;
    int*   row_ptr = (int*)d_ws + o_rowptr;
    float* dis     = (float*)d_ws + o_dis;
    int*   adj_src = (int*)d_ws + o_adjs;
    float* adj_norm= (float*)d_ws + o_adjn;
    float* hA      = (float*)d_ws + o_hA;
    float* hB      = (float*)d_ws + o_hB;

    // zero counts..cursor region in one go (contiguous in layout)
    int nz = (int)(o_cursor + N);
    zero_ints<<<(nz + 255) / 256, 256, 0, stream>>>((int*)d_ws, nz);

    count_deg<<<(E + 255) / 256, 256, 0, stream>>>(e_dst, E, counts);
    compute_dis<<<(N + 255) / 256, 256, 0, stream>>>(counts, dis, N);
    scan_rowptr<<<1, 1024, 0, stream>>>(counts, row_ptr, N);
    fill_adj<<<(E + 255) / 256, 256, 0, stream>>>(e_src, e_dst, E, dis, row_ptr,
                                                  cursor, adj_src, adj_norm);

    const int gemm_blocks = 1024;                 // 4096 waves, ~24 nodes each
    const int total_waves = gemm_blocks * 4;
    const int agg_blocks = (N + 3) / 4;           // wave per node

    gemm64<<<gemm_blocks, 256, 0, stream>>>(x, W1, hA, N, total_waves);
    aggregate<<<agg_blocks, 256, 0, stream>>>(hA, row_ptr, adj_src, adj_norm, dis, b1, hB, N);

    gemm64<<<gemm_blocks, 256, 0, stream>>>(hB, W2, hA, N, total_waves);
    aggregate<<<agg_blocks, 256, 0, stream>>>(hA, row_ptr, adj_src, adj_norm, dis, b2, hB, N);

    gemm64<<<gemm_blocks, 256, 0, stream>>>(hB, W3, hA, N, total_waves);
    aggregate<<<agg_blocks, 256, 0, stream>>>(hA, row_ptr, adj_src, adj_norm, dis, b3, hB, N);

    pool_final<<<G, 256, 0, stream>>>(hB, batch, N, lin_w, lin_b, out);
}

// Round 2
// 683.917 us; speedup vs baseline: 1.2237x; 1.2237x over previous
//
#include <hip/hip_runtime.h>

#define D 64

static __device__ __forceinline__ float bcast_lane(float x, int k) {
    return __int_as_float(__builtin_amdgcn_readlane(__float_as_int(x), k));
}

__global__ void zero_ints(int* __restrict__ p, int n) {
    int i = blockIdx.x * blockDim.x + threadIdx.x;
    if (i < n) p[i] = 0;
}

__global__ void count_deg(const int* __restrict__ dst, int E, int* __restrict__ counts) {
    int e = blockIdx.x * blockDim.x + threadIdx.x;
    if (e < E) atomicAdd(&counts[dst[e]], 1);
}

__global__ void compute_dis(const int* __restrict__ counts, float* __restrict__ dis, int N) {
    int i = blockIdx.x * blockDim.x + threadIdx.x;
    if (i < N) dis[i] = rsqrtf((float)(counts[i] + 1));  // +1 self-loop
}

// ---------- 3-phase parallel exclusive scan of counts -> row_ptr ----------

// Phase 1: per-block (256 elems) sums
__global__ void scan_phase1(const int* __restrict__ counts, int N, int* __restrict__ bsum) {
    __shared__ int red[8];
    int i = blockIdx.x * 256 + threadIdx.x;
    int v = (i < N) ? counts[i] : 0;
    // wave reduce
#pragma unroll
    for (int off = 32; off >= 1; off >>= 1) v += __shfl_down(v, off, 64);
    int lane = threadIdx.x & 63, wv = threadIdx.x >> 6;
    if (lane == 0) red[wv] = v;
    __syncthreads();
    if (threadIdx.x == 0) bsum[blockIdx.x] = red[0] + red[1] + red[2] + red[3];
}

// Phase 2: single block scans B (<=512) block sums -> exclusive prefix, plus total at [B]
__global__ void scan_phase2(const int* __restrict__ bsum, int B, int* __restrict__ bpre) {
    __shared__ int s[512];
    int t = threadIdx.x;
    s[t] = (t < B) ? bsum[t] : 0;
    __syncthreads();
    for (int off = 1; off < 512; off <<= 1) {
        int v = (t >= off) ? s[t - off] : 0;
        __syncthreads();
        s[t] += v;
        __syncthreads();
    }
    if (t < B) bpre[t] = (t == 0) ? 0 : s[t - 1];
    if (t == 0) bpre[B] = s[511];
}

// Phase 3: per-block local exclusive scan + block offset -> row_ptr
__global__ void scan_phase3(const int* __restrict__ counts, int N, int B,
                            const int* __restrict__ bpre, int* __restrict__ row_ptr) {
    __shared__ int wsum[4];
    int t = threadIdx.x;
    int i = blockIdx.x * 256 + t;
    int orig = (i < N) ? counts[i] : 0;
    int val = orig;
    int lane = t & 63, wv = t >> 6;
    // wave inclusive scan
#pragma unroll
    for (int off = 1; off < 64; off <<= 1) {
        int u = __shfl_up(val, off, 64);
        if (lane >= off) val += u;
    }
    if (lane == 63) wsum[wv] = val;
    __syncthreads();
    int wo = 0;
#pragma unroll
    for (int w = 0; w < 4; w++) if (w < wv) wo += wsum[w];
    if (i < N) row_ptr[i] = bpre[blockIdx.x] + wo + (val - orig);
    if (blockIdx.x == 0 && t == 0) row_ptr[N] = bpre[B];
}

// --------------------------------------------------------------------------

__global__ void fill_adj(const int* __restrict__ src, const int* __restrict__ dst, int E,
                         const float* __restrict__ dis, const int* __restrict__ row_ptr,
                         int* __restrict__ cursor, int* __restrict__ adj_src,
                         float* __restrict__ adj_norm) {
    int e = blockIdx.x * blockDim.x + threadIdx.x;
    if (e < E) {
        int s = src[e], d = dst[e];
        int pos = atomicAdd(&cursor[d], 1);
        int idx = row_ptr[d] + pos;
        adj_src[idx] = s;
        adj_norm[idx] = dis[s] * dis[d];
    }
}

// out[n][d] = sum_k in[n][k] * W[k][d]   (bias fused into aggregate)
// W staged in LDS (16 KB); lane = output dim d; x broadcast via readlane.
// 2 nodes per k-loop to halve ds_read count. Low VGPR -> no spill.
__global__ __launch_bounds__(256) void gemm64(const float* __restrict__ in,
                                              const float* __restrict__ Wg,
                                              float* __restrict__ out, int N, int total_waves) {
    __shared__ float Wlds[D * D];
#pragma unroll
    for (int r = 0; r < 16; r++) Wlds[r * 256 + threadIdx.x] = Wg[r * 256 + threadIdx.x];
    __syncthreads();

    int lane = threadIdx.x & 63;
    int wave = (blockIdx.x * blockDim.x + threadIdx.x) >> 6;

    for (int n = wave; n < N; n += 2 * total_waves) {
        int n2 = n + total_waves;
        bool has2 = (n2 < N);
        float x0 = in[n * D + lane];
        float x1 = has2 ? in[n2 * D + lane] : 0.f;
        float a0 = 0.f, a1 = 0.f;
#pragma unroll
        for (int k = 0; k < D; k++) {
            float wv = Wlds[k * D + lane];
            a0 += bcast_lane(x0, k) * wv;
            a1 += bcast_lane(x1, k) * wv;
        }
        out[n * D + lane] = a0;
        if (has2) out[n2 * D + lane] = a1;
    }
}

// Wave-per-node CSR gather + self-loop + bias + relu. No atomics.
__global__ __launch_bounds__(256) void aggregate(const float* __restrict__ h,
                                                 const int* __restrict__ row_ptr,
                                                 const int* __restrict__ adj_src,
                                                 const float* __restrict__ adj_norm,
                                                 const float* __restrict__ dis,
                                                 const float* __restrict__ bias,
                                                 float* __restrict__ out, int N) {
    int lane = threadIdx.x & 63;
    int wave = (blockIdx.x * blockDim.x + threadIdx.x) >> 6;
    if (wave >= N) return;
    int n = wave;
    float dn = dis[n];
    float acc = dn * dn * h[n * D + lane];
    int e = row_ptr[n];
    int e_end = row_ptr[n + 1];
    for (; e + 4 <= e_end; e += 4) {
        int a0 = adj_src[e], a1 = adj_src[e + 1], a2 = adj_src[e + 2], a3 = adj_src[e + 3];
        float w0 = adj_norm[e], w1 = adj_norm[e + 1], w2 = adj_norm[e + 2], w3 = adj_norm[e + 3];
        float r0 = h[a0 * D + lane];
        float r1 = h[a1 * D + lane];
        float r2 = h[a2 * D + lane];
        float r3 = h[a3 * D + lane];
        acc += w0 * r0;
        acc += w1 * r1;
        acc += w2 * r2;
        acc += w3 * r3;
    }
    for (; e < e_end; e++) acc += adj_norm[e] * h[adj_src[e] * D + lane];
    float v = acc + bias[lane];
    out[n * D + lane] = fmaxf(v, 0.f);
}

// One block per graph: binary-search segment bounds in sorted batch,
// register-accumulate pooled row, fuse final linear. No atomics.
__global__ __launch_bounds__(256) void pool_final(const float* __restrict__ h,
                                                  const int* __restrict__ batch, int N,
                                                  const float* __restrict__ lin_w,
                                                  const float* __restrict__ lin_b,
                                                  float* __restrict__ out) {
    int g = blockIdx.x;
    int lane = threadIdx.x & 63;
    int wv = threadIdx.x >> 6;

    int lo = 0, hi = N;
    while (lo < hi) { int mid = (lo + hi) >> 1; if (batch[mid] < g) lo = mid + 1; else hi = mid; }
    int start = lo;
    lo = 0; hi = N;
    while (lo < hi) { int mid = (lo + hi) >> 1; if (batch[mid] < g + 1) lo = mid + 1; else hi = mid; }
    int end = lo;

    float acc = 0.f;
    for (int n = start + wv; n < end; n += 4) acc += h[n * D + lane];

    __shared__ float red[4][D];
    red[wv][lane] = acc;
    __syncthreads();
    if (wv == 0) {
        float t = red[0][lane] + red[1][lane] + red[2][lane] + red[3][lane];
        t *= lin_w[lane];
#pragma unroll
        for (int off = 32; off >= 1; off >>= 1) t += __shfl_down(t, off, 64);
        if (lane == 0) out[g] = t + lin_b[0];
    }
}

extern "C" void kernel_launch(void* const* d_in, const int* in_sizes, int n_in,
                              void* d_out, int out_size, void* d_ws, size_t ws_size,
                              hipStream_t stream) {
    const float* x      = (const float*)d_in[0];
    const int*   edges  = (const int*)d_in[1];
    const int*   batch  = (const int*)d_in[2];
    const float* W1     = (const float*)d_in[3];
    const float* b1     = (const float*)d_in[4];
    const float* W2     = (const float*)d_in[5];
    const float* b2     = (const float*)d_in[6];
    const float* W3     = (const float*)d_in[7];
    const float* b3     = (const float*)d_in[8];
    const float* lin_w  = (const float*)d_in[9];
    const float* lin_b  = (const float*)d_in[10];
    float* out = (float*)d_out;

    const int N = in_sizes[2];        // 100000
    const int E = in_sizes[1] / 2;    // 1600000
    const int G = out_size;           // 64 graphs
    const int B = (N + 255) / 256;    // scan blocks (391)

    const int* e_src = edges;         // edge_index[0]
    const int* e_dst = edges + E;     // edge_index[1]

    // workspace layout (element offsets, 4B elems), 64-elem aligned
    auto al = [](long v) { return (v + 63) & ~63L; };
    long o_counts = 0;
    long o_cursor = al(o_counts + N);
    long o_rowptr = al(o_cursor + N);
    long o_dis    = al(o_rowptr + N + 1);
    long o_bsum   = al(o_dis + N);
    long o_bpre   = al(o_bsum + B);
    long o_adjs   = al(o_bpre + B + 1);
    long o_adjn   = al(o_adjs + E);
    long o_hA     = al(o_adjn + E);
    long o_hB     = o_hA + (long)N * D;

    int*   counts  = (int*)d_ws + o_counts;
    int*   cursor  = (int*)d_ws + o_cursor;
    int*   row_ptr = (int*)d_ws + o_rowptr;
    float* dis     = (float*)d_ws + o_dis;
    int*   bsum    = (int*)d_ws + o_bsum;
    int*   bpre    = (int*)d_ws + o_bpre;
    int*   adj_src = (int*)d_ws + o_adjs;
    float* adj_norm= (float*)d_ws + o_adjn;
    float* hA      = (float*)d_ws + o_hA;
    float* hB      = (float*)d_ws + o_hB;

    // zero counts..cursor region in one go (contiguous in layout)
    int nz = (int)(o_cursor + N);
    zero_ints<<<(nz + 255) / 256, 256, 0, stream>>>((int*)d_ws, nz);

    count_deg<<<(E + 255) / 256, 256, 0, stream>>>(e_dst, E, counts);
    compute_dis<<<(N + 255) / 256, 256, 0, stream>>>(counts, dis, N);
    scan_phase1<<<B, 256, 0, stream>>>(counts, N, bsum);
    scan_phase2<<<1, 512, 0, stream>>>(bsum, B, bpre);
    scan_phase3<<<B, 256, 0, stream>>>(counts, N, B, bpre, row_ptr);
    fill_adj<<<(E + 255) / 256, 256, 0, stream>>>(e_src, e_dst, E, dis, row_ptr,
                                                  cursor, adj_src, adj_norm);

    const int gemm_blocks = 1024;
    const int total_waves = gemm_blocks * 4;
    const int agg_blocks = (N + 3) / 4;           // wave per node

    gemm64<<<gemm_blocks, 256, 0, stream>>>(x, W1, hA, N, total_waves);
    aggregate<<<agg_blocks, 256, 0, stream>>>(hA, row_ptr, adj_src, adj_norm, dis, b1, hB, N);

    gemm64<<<gemm_blocks, 256, 0, stream>>>(hB, W2, hA, N, total_waves);
    aggregate<<<agg_blocks, 256, 0, stream>>>(hA, row_ptr, adj_src, adj_norm, dis, b2, hB, N);

    gemm64<<<gemm_blocks, 256, 0, stream>>>(hB, W3, hA, N, total_waves);
    aggregate<<<agg_blocks, 256, 0, stream>>>(hA, row_ptr, adj_src, adj_norm, dis, b3, hB, N);

    pool_final<<<G, 256, 0, stream>>>(hB, batch, N, lin_w, lin_b, out);
}

// Round 3
// 601.033 us; speedup vs baseline: 1.3925x; 1.1379x over previous
//
#include <hip/hip_runtime.h>

#define D 64

static __device__ __forceinline__ float bcast_lane(float x, int k) {
    return __int_as_float(__builtin_amdgcn_readlane(__float_as_int(x), k));
}

__global__ void zero_ints(int* __restrict__ p, int n) {
    int i = blockIdx.x * blockDim.x + threadIdx.x;
    if (i < n) p[i] = 0;
}

__global__ void count_deg(const int* __restrict__ dst, int E, int* __restrict__ counts) {
    int e = blockIdx.x * blockDim.x + threadIdx.x;
    if (e < E) atomicAdd(&counts[dst[e]], 1);
}

__global__ void compute_dis(const int* __restrict__ counts, float* __restrict__ dis, int N) {
    int i = blockIdx.x * blockDim.x + threadIdx.x;
    if (i < N) dis[i] = rsqrtf((float)(counts[i] + 1));  // +1 self-loop
}

// ---------- 3-phase parallel exclusive scan of counts -> row_ptr ----------

__global__ void scan_phase1(const int* __restrict__ counts, int N, int* __restrict__ bsum) {
    __shared__ int red[8];
    int i = blockIdx.x * 256 + threadIdx.x;
    int v = (i < N) ? counts[i] : 0;
#pragma unroll
    for (int off = 32; off >= 1; off >>= 1) v += __shfl_down(v, off, 64);
    int lane = threadIdx.x & 63, wv = threadIdx.x >> 6;
    if (lane == 0) red[wv] = v;
    __syncthreads();
    if (threadIdx.x == 0) bsum[blockIdx.x] = red[0] + red[1] + red[2] + red[3];
}

__global__ void scan_phase2(const int* __restrict__ bsum, int B, int* __restrict__ bpre) {
    __shared__ int s[512];
    int t = threadIdx.x;
    s[t] = (t < B) ? bsum[t] : 0;
    __syncthreads();
    for (int off = 1; off < 512; off <<= 1) {
        int v = (t >= off) ? s[t - off] : 0;
        __syncthreads();
        s[t] += v;
        __syncthreads();
    }
    if (t < B) bpre[t] = (t == 0) ? 0 : s[t - 1];
    if (t == 0) bpre[B] = s[511];
}

__global__ void scan_phase3(const int* __restrict__ counts, int N, int B,
                            const int* __restrict__ bpre, int* __restrict__ row_ptr) {
    __shared__ int wsum[4];
    int t = threadIdx.x;
    int i = blockIdx.x * 256 + t;
    int orig = (i < N) ? counts[i] : 0;
    int val = orig;
    int lane = t & 63, wv = t >> 6;
#pragma unroll
    for (int off = 1; off < 64; off <<= 1) {
        int u = __shfl_up(val, off, 64);
        if (lane >= off) val += u;
    }
    if (lane == 63) wsum[wv] = val;
    __syncthreads();
    int wo = 0;
#pragma unroll
    for (int w = 0; w < 4; w++) if (w < wv) wo += wsum[w];
    if (i < N) row_ptr[i] = bpre[blockIdx.x] + wo + (val - orig);
    if (blockIdx.x == 0 && t == 0) row_ptr[N] = bpre[B];
}

// --------------------------------------------------------------------------

// CSR fill: only adj_src (4 B/edge scatter); norm computed on the fly later.
__global__ void fill_adj(const int* __restrict__ src, const int* __restrict__ dst, int E,
                         const int* __restrict__ row_ptr,
                         int* __restrict__ cursor, int* __restrict__ adj_src) {
    int e = blockIdx.x * blockDim.x + threadIdx.x;
    if (e < E) {
        int s = src[e], d = dst[e];
        int pos = atomicAdd(&cursor[d], 1);
        adj_src[row_ptr[d] + pos] = s;
    }
}

// out[n][d] = sum_k in[n][k] * W[k][d]   (bias fused into aggregate)
__global__ __launch_bounds__(256) void gemm64(const float* __restrict__ in,
                                              const float* __restrict__ Wg,
                                              float* __restrict__ out, int N, int total_waves) {
    __shared__ float Wlds[D * D];
#pragma unroll
    for (int r = 0; r < 16; r++) Wlds[r * 256 + threadIdx.x] = Wg[r * 256 + threadIdx.x];
    __syncthreads();

    int lane = threadIdx.x & 63;
    int wave = (blockIdx.x * blockDim.x + threadIdx.x) >> 6;

    for (int n = wave; n < N; n += 2 * total_waves) {
        int n2 = n + total_waves;
        bool has2 = (n2 < N);
        float x0 = in[n * D + lane];
        float x1 = has2 ? in[n2 * D + lane] : 0.f;
        float a0 = 0.f, a1 = 0.f;
#pragma unroll
        for (int k = 0; k < D; k++) {
            float wv = Wlds[k * D + lane];
            a0 += bcast_lane(x0, k) * wv;
            a1 += bcast_lane(x1, k) * wv;
        }
        out[n * D + lane] = a0;
        if (has2) out[n2 * D + lane] = a1;
    }
}

// Wave-per-node CSR gather; norm = dis[src]*dis[dst] computed on the fly
// with dis[dst] factored out of the sum. Fused bias + relu. No atomics.
__global__ __launch_bounds__(256) void aggregate(const float* __restrict__ h,
                                                 const int* __restrict__ row_ptr,
                                                 const int* __restrict__ adj_src,
                                                 const float* __restrict__ dis,
                                                 const float* __restrict__ bias,
                                                 float* __restrict__ out, int N) {
    int lane = threadIdx.x & 63;
    int wave = (blockIdx.x * blockDim.x + threadIdx.x) >> 6;
    if (wave >= N) return;
    int n = wave;
    float dn = dis[n];
    float hn = h[n * D + lane];
    float acc = 0.f;
    int e = row_ptr[n];
    int e_end = row_ptr[n + 1];
    for (; e + 4 <= e_end; e += 4) {
        int a0 = adj_src[e], a1 = adj_src[e + 1], a2 = adj_src[e + 2], a3 = adj_src[e + 3];
        float s0 = dis[a0], s1 = dis[a1], s2 = dis[a2], s3 = dis[a3];
        float r0 = h[a0 * D + lane];
        float r1 = h[a1 * D + lane];
        float r2 = h[a2 * D + lane];
        float r3 = h[a3 * D + lane];
        acc += s0 * r0;
        acc += s1 * r1;
        acc += s2 * r2;
        acc += s3 * r3;
    }
    for (; e < e_end; e++) { int a = adj_src[e]; acc += dis[a] * h[a * D + lane]; }
    float v = dn * acc + dn * dn * hn + bias[lane];
    out[n * D + lane] = fmaxf(v, 0.f);
}

// Phase 1 of pool: grid-chunked over sorted nodes; per-wave run accumulation,
// one atomicAdd per (graph-run, lane) per wave.
__global__ __launch_bounds__(256) void pool_partial(const float* __restrict__ h,
                                                    const int* __restrict__ batch, int N,
                                                    int chunk, float* __restrict__ pooled) {
    int lane = threadIdx.x & 63;
    int wv = threadIdx.x >> 6;
    int c0 = blockIdx.x * chunk;
    int c1 = min(c0 + chunk, N);
    int g_cur = -1;
    float acc = 0.f;
    for (int n = c0 + wv; n < c1; n += 4) {
        int g = batch[n];
        if (g != g_cur) {
            if (g_cur >= 0) atomicAdd(&pooled[g_cur * D + lane], acc);
            g_cur = g;
            acc = 0.f;
        }
        acc += h[n * D + lane];
    }
    if (g_cur >= 0) atomicAdd(&pooled[g_cur * D + lane], acc);
}

// Phase 2: one wave per graph, dot with lin_w.
__global__ void pool_linear(const float* __restrict__ pooled,
                            const float* __restrict__ lin_w,
                            const float* __restrict__ lin_b,
                            float* __restrict__ out, int G) {
    int lane = threadIdx.x & 63;
    int g = blockIdx.x * (blockDim.x >> 6) + (threadIdx.x >> 6);
    if (g >= G) return;
    float t = pooled[g * D + lane] * lin_w[lane];
#pragma unroll
    for (int off = 32; off >= 1; off >>= 1) t += __shfl_down(t, off, 64);
    if (lane == 0) out[g] = t + lin_b[0];
}

extern "C" void kernel_launch(void* const* d_in, const int* in_sizes, int n_in,
                              void* d_out, int out_size, void* d_ws, size_t ws_size,
                              hipStream_t stream) {
    const float* x      = (const float*)d_in[0];
    const int*   edges  = (const int*)d_in[1];
    const int*   batch  = (const int*)d_in[2];
    const float* W1     = (const float*)d_in[3];
    const float* b1     = (const float*)d_in[4];
    const float* W2     = (const float*)d_in[5];
    const float* b2     = (const float*)d_in[6];
    const float* W3     = (const float*)d_in[7];
    const float* b3     = (const float*)d_in[8];
    const float* lin_w  = (const float*)d_in[9];
    const float* lin_b  = (const float*)d_in[10];
    float* out = (float*)d_out;

    const int N = in_sizes[2];        // 100000
    const int E = in_sizes[1] / 2;    // 1600000
    const int G = out_size;           // 64 graphs
    const int B = (N + 255) / 256;    // scan blocks (391)

    const int* e_src = edges;         // edge_index[0]
    const int* e_dst = edges + E;     // edge_index[1]

    // workspace layout (element offsets, 4B elems), 64-elem aligned.
    // counts, cursor, pooled contiguous at front so one zero_ints covers all.
    auto al = [](long v) { return (v + 63) & ~63L; };
    long o_counts = 0;
    long o_cursor = al(o_counts + N);
    long o_pooled = al(o_cursor + N);
    long o_rowptr = al(o_pooled + (long)G * D);
    long o_dis    = al(o_rowptr + N + 1);
    long o_bsum   = al(o_dis + N);
    long o_bpre   = al(o_bsum + B);
    long o_adjs   = al(o_bpre + B + 1);
    long o_hA     = al(o_adjs + E);
    long o_hB     = o_hA + (long)N * D;

    int*   counts  = (int*)d_ws + o_counts;
    int*   cursor  = (int*)d_ws + o_cursor;
    float* pooled  = (float*)d_ws + o_pooled;
    int*   row_ptr = (int*)d_ws + o_rowptr;
    float* dis     = (float*)d_ws + o_dis;
    int*   bsum    = (int*)d_ws + o_bsum;
    int*   bpre    = (int*)d_ws + o_bpre;
    int*   adj_src = (int*)d_ws + o_adjs;
    float* hA      = (float*)d_ws + o_hA;
    float* hB      = (float*)d_ws + o_hB;

    // zero counts + cursor + pooled in one launch (contiguous region)
    int nz = (int)(o_pooled + (long)G * D);
    zero_ints<<<(nz + 255) / 256, 256, 0, stream>>>((int*)d_ws, nz);

    count_deg<<<(E + 255) / 256, 256, 0, stream>>>(e_dst, E, counts);
    compute_dis<<<(N + 255) / 256, 256, 0, stream>>>(counts, dis, N);
    scan_phase1<<<B, 256, 0, stream>>>(counts, N, bsum);
    scan_phase2<<<1, 512, 0, stream>>>(bsum, B, bpre);
    scan_phase3<<<B, 256, 0, stream>>>(counts, N, B, bpre, row_ptr);
    fill_adj<<<(E + 255) / 256, 256, 0, stream>>>(e_src, e_dst, E, row_ptr, cursor, adj_src);

    const int gemm_blocks = 1024;
    const int total_waves = gemm_blocks * 4;
    const int agg_blocks = (N + 3) / 4;           // wave per node

    gemm64<<<gemm_blocks, 256, 0, stream>>>(x, W1, hA, N, total_waves);
    aggregate<<<agg_blocks, 256, 0, stream>>>(hA, row_ptr, adj_src, dis, b1, hB, N);

    gemm64<<<gemm_blocks, 256, 0, stream>>>(hB, W2, hA, N, total_waves);
    aggregate<<<agg_blocks, 256, 0, stream>>>(hA, row_ptr, adj_src, dis, b2, hB, N);

    gemm64<<<gemm_blocks, 256, 0, stream>>>(hB, W3, hA, N, total_waves);
    aggregate<<<agg_blocks, 256, 0, stream>>>(hA, row_ptr, adj_src, dis, b3, hB, N);

    // pool: 512 chunks for parallelism, then tiny linear
    const int pool_blocks = 512;
    const int chunk = (N + pool_blocks - 1) / pool_blocks;
    pool_partial<<<pool_blocks, 256, 0, stream>>>(hB, batch, N, chunk, pooled);
    pool_linear<<<(G + 3) / 4, 256, 0, stream>>>(pooled, lin_w, lin_b, out, G);
}

// Round 4
// 518.644 us; speedup vs baseline: 1.6137x; 1.1589x over previous
//
#include <hip/hip_runtime.h>

#define D 64
#define NBMAX 512      // max buckets (nodes/256, N<=131072)
#define BCAP 5120      // per-bucket capacity; mean E/nb=4092, sigma~64 -> 16-sigma margin

static __device__ __forceinline__ float bcast_lane(float x, int k) {
    return __int_as_float(__builtin_amdgcn_readlane(__float_as_int(x), k));
}

__global__ void zero_ints(int* __restrict__ p, int n) {
    int i = blockIdx.x * blockDim.x + threadIdx.x;
    if (i < n) p[i] = 0;
}

// Bin edges into buckets of 256 consecutive dst nodes. Per-block LDS histogram
// + one bulk atomic reservation per (block,bucket) -> writes to each bucket
// region come from one CU in a tight window (lines fill inside one XCD L2).
__global__ __launch_bounds__(256) void bucket_scatter(const int* __restrict__ src,
                                                      const int* __restrict__ dst, int E,
                                                      int nb, int* __restrict__ gcursor,
                                                      unsigned long long* __restrict__ bpair) {
    __shared__ int lhist[NBMAX];
    __shared__ int lbase[NBMAX];
    int t = threadIdx.x;
    for (int i = t; i < nb; i += 256) lhist[i] = 0;
    __syncthreads();
    int e0 = blockIdx.x * 4096, e1 = min(e0 + 4096, E);
    for (int e = e0 + t; e < e1; e += 256) atomicAdd(&lhist[dst[e] >> 8], 1);
    __syncthreads();
    for (int i = t; i < nb; i += 256) {
        int c = lhist[i];
        lbase[i] = c ? atomicAdd(&gcursor[i], c) : 0;
        lhist[i] = 0;
    }
    __syncthreads();
    for (int e = e0 + t; e < e1; e += 256) {
        int d = dst[e];
        int b = d >> 8;
        int r = lbase[b] + atomicAdd(&lhist[b], 1);
        if (r < BCAP)
            bpair[(long)b * BCAP + r] =
                ((unsigned long long)(unsigned)d << 32) | (unsigned)src[e];
    }
}

// Exclusive scan of nb (<512) bucket counts -> gbase, total at gbase[nb].
__global__ void scan_buckets(const int* __restrict__ gcursor, int B, int* __restrict__ gbase) {
    __shared__ int s[512];
    int t = threadIdx.x;
    s[t] = (t < B) ? gcursor[t] : 0;
    __syncthreads();
    for (int off = 1; off < 512; off <<= 1) {
        int v = (t >= off) ? s[t - off] : 0;
        __syncthreads();
        s[t] += v;
        __syncthreads();
    }
    if (t < B) gbase[t] = (t == 0) ? 0 : s[t - 1];
    if (t == 0) gbase[B] = s[511];
}

// One block per bucket: local histogram + scan in LDS, emit row_ptr/dis
// (coalesced) and adj_src (scatter confined to a ~16KB L2-local window).
__global__ __launch_bounds__(256) void bucket_build(const unsigned long long* __restrict__ bpair,
                                                    int nb, int N,
                                                    const int* __restrict__ gcursor,
                                                    const int* __restrict__ gbase,
                                                    int* __restrict__ row_ptr,
                                                    float* __restrict__ dis,
                                                    int* __restrict__ adj_src) {
    __shared__ int hist[256];
    __shared__ int cur[256];
    __shared__ int wsum[4];
    int b = blockIdx.x, t = threadIdx.x;
    int node_base = b << 8;
    int cnt = gcursor[b];
    if (cnt > BCAP) cnt = BCAP;
    int ebase = gbase[b];
    const unsigned long long* bp = bpair + (long)b * BCAP;

    hist[t] = 0;
    __syncthreads();
    for (int i = t; i < cnt; i += 256) {
        int d = (int)(bp[i] >> 32);
        atomicAdd(&hist[d - node_base], 1);
    }
    __syncthreads();
    int val = hist[t];
    int lane = t & 63, wv = t >> 6;
    int v = val;
#pragma unroll
    for (int off = 1; off < 64; off <<= 1) {
        int u = __shfl_up(v, off, 64);
        if (lane >= off) v += u;
    }
    if (lane == 63) wsum[wv] = v;
    __syncthreads();
    int wo = 0;
#pragma unroll
    for (int w = 0; w < 4; w++)
        if (w < wv) wo += wsum[w];
    int excl = wo + v - val;
    int node = node_base + t;
    if (node < N) {
        row_ptr[node] = ebase + excl;
        dis[node] = rsqrtf((float)(val + 1));  // +1 self-loop
    }
    cur[t] = ebase + excl;
    __syncthreads();
    for (int i = t; i < cnt; i += 256) {
        unsigned long long p = bp[i];
        int d = (int)(p >> 32);
        int pos = atomicAdd(&cur[d - node_base], 1);
        adj_src[pos] = (int)(p & 0xffffffffu);
    }
    if (b == 0 && t == 0) row_ptr[N] = gbase[nb];
}

// Fused GCN layer using A(xW) = (Ax)W:
// y = dn*(sum_a dis[a]*in[a]) + dn^2*in[n]   (gather, 1 reg/lane)
// out = relu(y @ W + b)                       (readlane chain vs LDS-resident W)
__global__ __launch_bounds__(256) void fused_layer(const float* __restrict__ in,
                                                   const int* __restrict__ row_ptr,
                                                   const int* __restrict__ adj_src,
                                                   const float* __restrict__ dis,
                                                   const float* __restrict__ Wg,
                                                   const float* __restrict__ bias,
                                                   float* __restrict__ out, int N,
                                                   int total_waves) {
    __shared__ float Wlds[D * D];
#pragma unroll
    for (int r = 0; r < 16; r++) Wlds[r * 256 + threadIdx.x] = Wg[r * 256 + threadIdx.x];
    int lane = threadIdx.x & 63;
    float bl = bias[lane];
    __syncthreads();

    int wave = (blockIdx.x * blockDim.x + threadIdx.x) >> 6;
    for (int n = wave; n < N; n += total_waves) {
        float dn = dis[n];
        float acc = dn * in[n * D + lane];
        int e = row_ptr[n], e_end = row_ptr[n + 1];
        for (; e + 4 <= e_end; e += 4) {
            int a0 = adj_src[e], a1 = adj_src[e + 1], a2 = adj_src[e + 2], a3 = adj_src[e + 3];
            float s0 = dis[a0], s1 = dis[a1], s2 = dis[a2], s3 = dis[a3];
            float r0 = in[a0 * D + lane];
            float r1 = in[a1 * D + lane];
            float r2 = in[a2 * D + lane];
            float r3 = in[a3 * D + lane];
            acc += s0 * r0;
            acc += s1 * r1;
            acc += s2 * r2;
            acc += s3 * r3;
        }
        for (; e < e_end; e++) {
            int a = adj_src[e];
            acc += dis[a] * in[a * D + lane];
        }
        float y = dn * acc;
        float o = bl;
#pragma unroll
        for (int k = 0; k < D; k++) o = fmaf(bcast_lane(y, k), Wlds[k * D + lane], o);
        out[n * D + lane] = fmaxf(o, 0.f);
    }
}

// Pool phase 1: grid-chunked over sorted nodes; per-wave run accumulation,
// one atomicAdd per (graph-run, lane) per wave.
__global__ __launch_bounds__(256) void pool_partial(const float* __restrict__ h,
                                                    const int* __restrict__ batch, int N,
                                                    int chunk, float* __restrict__ pooled) {
    int lane = threadIdx.x & 63;
    int wv = threadIdx.x >> 6;
    int c0 = blockIdx.x * chunk;
    int c1 = min(c0 + chunk, N);
    int g_cur = -1;
    float acc = 0.f;
    for (int n = c0 + wv; n < c1; n += 4) {
        int g = batch[n];
        if (g != g_cur) {
            if (g_cur >= 0) atomicAdd(&pooled[g_cur * D + lane], acc);
            g_cur = g;
            acc = 0.f;
        }
        acc += h[n * D + lane];
    }
    if (g_cur >= 0) atomicAdd(&pooled[g_cur * D + lane], acc);
}

// Pool phase 2: one wave per graph, dot with lin_w.
__global__ void pool_linear(const float* __restrict__ pooled,
                            const float* __restrict__ lin_w,
                            const float* __restrict__ lin_b,
                            float* __restrict__ out, int G) {
    int lane = threadIdx.x & 63;
    int g = blockIdx.x * (blockDim.x >> 6) + (threadIdx.x >> 6);
    if (g >= G) return;
    float t = pooled[g * D + lane] * lin_w[lane];
#pragma unroll
    for (int off = 32; off >= 1; off >>= 1) t += __shfl_down(t, off, 64);
    if (lane == 0) out[g] = t + lin_b[0];
}

extern "C" void kernel_launch(void* const* d_in, const int* in_sizes, int n_in,
                              void* d_out, int out_size, void* d_ws, size_t ws_size,
                              hipStream_t stream) {
    const float* x      = (const float*)d_in[0];
    const int*   edges  = (const int*)d_in[1];
    const int*   batch  = (const int*)d_in[2];
    const float* W1     = (const float*)d_in[3];
    const float* b1     = (const float*)d_in[4];
    const float* W2     = (const float*)d_in[5];
    const float* b2     = (const float*)d_in[6];
    const float* W3     = (const float*)d_in[7];
    const float* b3     = (const float*)d_in[8];
    const float* lin_w  = (const float*)d_in[9];
    const float* lin_b  = (const float*)d_in[10];
    float* out = (float*)d_out;

    const int N = in_sizes[2];        // 100000
    const int E = in_sizes[1] / 2;    // 1600000
    const int G = out_size;           // 64 graphs
    const int nb = (N + 255) >> 8;    // 391 buckets of 256 nodes

    const int* e_src = edges;         // edge_index[0]
    const int* e_dst = edges + E;     // edge_index[1]

    // workspace layout (4B-element offsets, 64-elem aligned)
    // gcursor + pooled contiguous at front -> single zero_ints.
    auto al = [](long v) { return (v + 63) & ~63L; };
    long o_gcur   = 0;                       // NBMAX ints
    long o_pooled = al(o_gcur + NBMAX);      // G*D floats
    long o_gbase  = al(o_pooled + (long)G * D);
    long o_rowptr = al(o_gbase + nb + 1);
    long o_dis    = al(o_rowptr + N + 1);
    long o_adjs   = al(o_dis + N);
    long o_hA     = al(o_adjs + E);          // also aliases bpair during preprocessing
    long o_hB     = o_hA + (long)N * D;

    int*   gcursor = (int*)d_ws + o_gcur;
    float* pooled  = (float*)d_ws + o_pooled;
    int*   gbase   = (int*)d_ws + o_gbase;
    int*   row_ptr = (int*)d_ws + o_rowptr;
    float* dis     = (float*)d_ws + o_dis;
    int*   adj_src = (int*)d_ws + o_adjs;
    float* hA      = (float*)d_ws + o_hA;
    float* hB      = (float*)d_ws + o_hB;
    // bpair (nb*BCAP ulongs = 16 MB) aliases hA (25.6 MB): dead before layer 2 writes hA.
    unsigned long long* bpair = (unsigned long long*)hA;

    // zero gcursor + pooled (contiguous)
    int nz = (int)(o_pooled + (long)G * D);
    zero_ints<<<(nz + 255) / 256, 256, 0, stream>>>((int*)d_ws, nz);

    // CSR build: bucket scatter -> scan -> per-bucket local build
    bucket_scatter<<<(E + 4095) / 4096, 256, 0, stream>>>(e_src, e_dst, E, nb, gcursor, bpair);
    scan_buckets<<<1, 512, 0, stream>>>(gcursor, nb, gbase);
    bucket_build<<<nb, 256, 0, stream>>>(bpair, nb, N, gcursor, gbase, row_ptr, dis, adj_src);

    // fused GCN layers: x -> hB -> hA -> hB
    const int fl_blocks = 2048;
    const int total_waves = fl_blocks * 4;
    fused_layer<<<fl_blocks, 256, 0, stream>>>(x,  row_ptr, adj_src, dis, W1, b1, hB, N, total_waves);
    fused_layer<<<fl_blocks, 256, 0, stream>>>(hB, row_ptr, adj_src, dis, W2, b2, hA, N, total_waves);
    fused_layer<<<fl_blocks, 256, 0, stream>>>(hA, row_ptr, adj_src, dis, W3, b3, hB, N, total_waves);

    // pool + final linear
    const int pool_blocks = 512;
    const int chunk = (N + pool_blocks - 1) / pool_blocks;
    pool_partial<<<pool_blocks, 256, 0, stream>>>(hB, batch, N, chunk, pooled);
    pool_linear<<<(G + 3) / 4, 256, 0, stream>>>(pooled, lin_w, lin_b, out, G);
}

// Round 5
// 497.334 us; speedup vs baseline: 1.6829x; 1.0428x over previous
//
#include <hip/hip_runtime.h>
#include <hip/hip_fp16.h>

#define D 64
#define NBMAX 512      // max buckets (nodes/256, N<=131072)
#define BCAP 5120      // per-bucket capacity; mean E/nb=4092, sigma~64 -> 16-sigma margin

static __device__ __forceinline__ float bcast_lane(float x, int k) {
    return __int_as_float(__builtin_amdgcn_readlane(__float_as_int(x), k));
}

__global__ void zero_ints(int* __restrict__ p, int n) {
    int i = blockIdx.x * blockDim.x + threadIdx.x;
    if (i < n) p[i] = 0;
}

// fp32 -> fp16 streaming convert (2 elems/thread via float2 -> half2)
__global__ void f32_to_f16(const float* __restrict__ in, __half* __restrict__ out, int n2) {
    int i = blockIdx.x * blockDim.x + threadIdx.x;
    if (i < n2) {
        float2 v = ((const float2*)in)[i];
        ((__half2*)out)[i] = __floats2half2_rn(v.x, v.y);
    }
}

// Bin edges into buckets of 256 consecutive dst nodes. Per-block LDS histogram
// + one bulk atomic reservation per (block,bucket) -> writes to each bucket
// region come from one CU in a tight window (lines fill inside one XCD L2).
__global__ __launch_bounds__(256) void bucket_scatter(const int* __restrict__ src,
                                                      const int* __restrict__ dst, int E,
                                                      int nb, int* __restrict__ gcursor,
                                                      unsigned long long* __restrict__ bpair) {
    __shared__ int lhist[NBMAX];
    __shared__ int lbase[NBMAX];
    int t = threadIdx.x;
    for (int i = t; i < nb; i += 256) lhist[i] = 0;
    __syncthreads();
    int e0 = blockIdx.x * 4096, e1 = min(e0 + 4096, E);
    for (int e = e0 + t; e < e1; e += 256) atomicAdd(&lhist[dst[e] >> 8], 1);
    __syncthreads();
    for (int i = t; i < nb; i += 256) {
        int c = lhist[i];
        lbase[i] = c ? atomicAdd(&gcursor[i], c) : 0;
        lhist[i] = 0;
    }
    __syncthreads();
    for (int e = e0 + t; e < e1; e += 256) {
        int d = dst[e];
        int b = d >> 8;
        int r = lbase[b] + atomicAdd(&lhist[b], 1);
        if (r < BCAP)
            bpair[(long)b * BCAP + r] =
                ((unsigned long long)(unsigned)d << 32) | (unsigned)src[e];
    }
}

// Exclusive scan of nb (<512) bucket counts -> gbase, total at gbase[nb].
__global__ void scan_buckets(const int* __restrict__ gcursor, int B, int* __restrict__ gbase) {
    __shared__ int s[512];
    int t = threadIdx.x;
    s[t] = (t < B) ? gcursor[t] : 0;
    __syncthreads();
    for (int off = 1; off < 512; off <<= 1) {
        int v = (t >= off) ? s[t - off] : 0;
        __syncthreads();
        s[t] += v;
        __syncthreads();
    }
    if (t < B) gbase[t] = (t == 0) ? 0 : s[t - 1];
    if (t == 0) gbase[B] = s[511];
}

// One block per bucket: local histogram + scan in LDS, emit row_ptr/dis
// (coalesced) and adj_src (scatter confined to a ~16KB L2-local window).
__global__ __launch_bounds__(256) void bucket_build(const unsigned long long* __restrict__ bpair,
                                                    int nb, int N,
                                                    const int* __restrict__ gcursor,
                                                    const int* __restrict__ gbase,
                                                    int* __restrict__ row_ptr,
                                                    float* __restrict__ dis,
                                                    int* __restrict__ adj_src) {
    __shared__ int hist[256];
    __shared__ int cur[256];
    __shared__ int wsum[4];
    int b = blockIdx.x, t = threadIdx.x;
    int node_base = b << 8;
    int cnt = gcursor[b];
    if (cnt > BCAP) cnt = BCAP;
    int ebase = gbase[b];
    const unsigned long long* bp = bpair + (long)b * BCAP;

    hist[t] = 0;
    __syncthreads();
    for (int i = t; i < cnt; i += 256) {
        int d = (int)(bp[i] >> 32);
        atomicAdd(&hist[d - node_base], 1);
    }
    __syncthreads();
    int val = hist[t];
    int lane = t & 63, wv = t >> 6;
    int v = val;
#pragma unroll
    for (int off = 1; off < 64; off <<= 1) {
        int u = __shfl_up(v, off, 64);
        if (lane >= off) v += u;
    }
    if (lane == 63) wsum[wv] = v;
    __syncthreads();
    int wo = 0;
#pragma unroll
    for (int w = 0; w < 4; w++)
        if (w < wv) wo += wsum[w];
    int excl = wo + v - val;
    int node = node_base + t;
    if (node < N) {
        row_ptr[node] = ebase + excl;
        dis[node] = rsqrtf((float)(val + 1));  // +1 self-loop
    }
    cur[t] = ebase + excl;
    __syncthreads();
    for (int i = t; i < cnt; i += 256) {
        unsigned long long p = bp[i];
        int d = (int)(p >> 32);
        int pos = atomicAdd(&cur[d - node_base], 1);
        adj_src[pos] = (int)(p & 0xffffffffu);
    }
    if (b == 0 && t == 0) row_ptr[N] = gbase[nb];
}

// Fused GCN layer using A(xW) = (Ax)W, fp16 storage / fp32 compute:
// y = dn*(sum_a dis[a]*in[a]) + dn^2*in[n]   (gather, 1 reg/lane)
// out = relu(y @ W + b)                       (readlane chain vs LDS-resident W)
__global__ __launch_bounds__(256) void fused_layer(const __half* __restrict__ in,
                                                   const int* __restrict__ row_ptr,
                                                   const int* __restrict__ adj_src,
                                                   const float* __restrict__ dis,
                                                   const float* __restrict__ Wg,
                                                   const float* __restrict__ bias,
                                                   __half* __restrict__ out, int N,
                                                   int total_waves) {
    __shared__ float Wlds[D * D];
#pragma unroll
    for (int r = 0; r < 16; r++) Wlds[r * 256 + threadIdx.x] = Wg[r * 256 + threadIdx.x];
    int lane = threadIdx.x & 63;
    float bl = bias[lane];
    __syncthreads();

    int wave = (blockIdx.x * blockDim.x + threadIdx.x) >> 6;
    for (int n = wave; n < N; n += total_waves) {
        float dn = dis[n];
        float acc = dn * __half2float(in[n * D + lane]);
        int e = row_ptr[n], e_end = row_ptr[n + 1];
        for (; e + 4 <= e_end; e += 4) {
            int a0 = adj_src[e], a1 = adj_src[e + 1], a2 = adj_src[e + 2], a3 = adj_src[e + 3];
            float s0 = dis[a0], s1 = dis[a1], s2 = dis[a2], s3 = dis[a3];
            float r0 = __half2float(in[a0 * D + lane]);
            float r1 = __half2float(in[a1 * D + lane]);
            float r2 = __half2float(in[a2 * D + lane]);
            float r3 = __half2float(in[a3 * D + lane]);
            acc += s0 * r0;
            acc += s1 * r1;
            acc += s2 * r2;
            acc += s3 * r3;
        }
        for (; e < e_end; e++) {
            int a = adj_src[e];
            acc += dis[a] * __half2float(in[a * D + lane]);
        }
        float y = dn * acc;
        float o = bl;
#pragma unroll
        for (int k = 0; k < D; k++) o = fmaf(bcast_lane(y, k), Wlds[k * D + lane], o);
        out[n * D + lane] = __float2half(fmaxf(o, 0.f));
    }
}

// Pool phase 1: grid-chunked over sorted nodes; per-wave run accumulation,
// one atomicAdd per (graph-run, lane) per wave.
__global__ __launch_bounds__(256) void pool_partial(const __half* __restrict__ h,
                                                    const int* __restrict__ batch, int N,
                                                    int chunk, float* __restrict__ pooled) {
    int lane = threadIdx.x & 63;
    int wv = threadIdx.x >> 6;
    int c0 = blockIdx.x * chunk;
    int c1 = min(c0 + chunk, N);
    int g_cur = -1;
    float acc = 0.f;
    for (int n = c0 + wv; n < c1; n += 4) {
        int g = batch[n];
        if (g != g_cur) {
            if (g_cur >= 0) atomicAdd(&pooled[g_cur * D + lane], acc);
            g_cur = g;
            acc = 0.f;
        }
        acc += __half2float(h[n * D + lane]);
    }
    if (g_cur >= 0) atomicAdd(&pooled[g_cur * D + lane], acc);
}

// Pool phase 2: one wave per graph, dot with lin_w.
__global__ void pool_linear(const float* __restrict__ pooled,
                            const float* __restrict__ lin_w,
                            const float* __restrict__ lin_b,
                            float* __restrict__ out, int G) {
    int lane = threadIdx.x & 63;
    int g = blockIdx.x * (blockDim.x >> 6) + (threadIdx.x >> 6);
    if (g >= G) return;
    float t = pooled[g * D + lane] * lin_w[lane];
#pragma unroll
    for (int off = 32; off >= 1; off >>= 1) t += __shfl_down(t, off, 64);
    if (lane == 0) out[g] = t + lin_b[0];
}

extern "C" void kernel_launch(void* const* d_in, const int* in_sizes, int n_in,
                              void* d_out, int out_size, void* d_ws, size_t ws_size,
                              hipStream_t stream) {
    const float* x      = (const float*)d_in[0];
    const int*   edges  = (const int*)d_in[1];
    const int*   batch  = (const int*)d_in[2];
    const float* W1     = (const float*)d_in[3];
    const float* b1     = (const float*)d_in[4];
    const float* W2     = (const float*)d_in[5];
    const float* b2     = (const float*)d_in[6];
    const float* W3     = (const float*)d_in[7];
    const float* b3     = (const float*)d_in[8];
    const float* lin_w  = (const float*)d_in[9];
    const float* lin_b  = (const float*)d_in[10];
    float* out = (float*)d_out;

    const int N = in_sizes[2];        // 100000
    const int E = in_sizes[1] / 2;    // 1600000
    const int G = out_size;           // 64 graphs
    const int nb = (N + 255) >> 8;    // 391 buckets of 256 nodes

    const int* e_src = edges;         // edge_index[0]
    const int* e_dst = edges + E;     // edge_index[1]

    // workspace layout (4B-element offsets, 64-elem aligned)
    // gcursor + pooled contiguous at front -> single zero_ints.
    auto al = [](long v) { return (v + 63) & ~63L; };
    long o_gcur   = 0;                       // NBMAX ints
    long o_pooled = al(o_gcur + NBMAX);      // G*D floats
    long o_gbase  = al(o_pooled + (long)G * D);
    long o_rowptr = al(o_gbase + nb + 1);
    long o_dis    = al(o_rowptr + N + 1);
    long o_adjs   = al(o_dis + N);
    long o_xh     = al(o_adjs + E);          // N*D halves (N*D/2 float slots)
    long o_hA     = al(o_xh + (long)N * D / 2);  // also aliases bpair (16MB < 25.6MB slot)
    long o_hB     = o_hA + (long)N * D;      // slots kept fp32-sized; used as half buffers

    int*    gcursor = (int*)d_ws + o_gcur;
    float*  pooled  = (float*)d_ws + o_pooled;
    int*    gbase   = (int*)d_ws + o_gbase;
    int*    row_ptr = (int*)d_ws + o_rowptr;
    float*  dis     = (float*)d_ws + o_dis;
    int*    adj_src = (int*)d_ws + o_adjs;
    __half* xh      = (__half*)((float*)d_ws + o_xh);
    __half* hA      = (__half*)((float*)d_ws + o_hA);
    __half* hB      = (__half*)((float*)d_ws + o_hB);
    // bpair (nb*BCAP ulongs = 16 MB) aliases hA slot (25.6 MB): dead before layer 2 writes hA.
    unsigned long long* bpair = (unsigned long long*)hA;

    // zero gcursor + pooled (contiguous)
    int nz = (int)(o_pooled + (long)G * D);
    zero_ints<<<(nz + 255) / 256, 256, 0, stream>>>((int*)d_ws, nz);

    // convert x to fp16 once
    int n2 = N * D / 2;
    f32_to_f16<<<(n2 + 255) / 256, 256, 0, stream>>>(x, xh, n2);

    // CSR build: bucket scatter -> scan -> per-bucket local build
    bucket_scatter<<<(E + 4095) / 4096, 256, 0, stream>>>(e_src, e_dst, E, nb, gcursor, bpair);
    scan_buckets<<<1, 512, 0, stream>>>(gcursor, nb, gbase);
    bucket_build<<<nb, 256, 0, stream>>>(bpair, nb, N, gcursor, gbase, row_ptr, dis, adj_src);

    // fused GCN layers: xh -> hB -> hA -> hB   (fp16 storage, fp32 compute)
    const int fl_blocks = 2048;
    const int total_waves = fl_blocks * 4;
    fused_layer<<<fl_blocks, 256, 0, stream>>>(xh, row_ptr, adj_src, dis, W1, b1, hB, N, total_waves);
    fused_layer<<<fl_blocks, 256, 0, stream>>>(hB, row_ptr, adj_src, dis, W2, b2, hA, N, total_waves);
    fused_layer<<<fl_blocks, 256, 0, stream>>>(hA, row_ptr, adj_src, dis, W3, b3, hB, N, total_waves);

    // pool + final linear
    const int pool_blocks = 512;
    const int chunk = (N + pool_blocks - 1) / pool_blocks;
    pool_partial<<<pool_blocks, 256, 0, stream>>>(hB, batch, N, chunk, pooled);
    pool_linear<<<(G + 3) / 4, 256, 0, stream>>>(pooled, lin_w, lin_b, out, G);
}

// Round 6
// 436.030 us; speedup vs baseline: 1.9195x; 1.1406x over previous
//
#include <hip/hip_runtime.h>
#include <hip/hip_fp16.h>

#define D 64
#define NBMAX 512      // max buckets (nodes/256, N<=131072)
#define BCAP 5120      // per-bucket capacity; mean E/nb=4092, sigma~64 -> 16-sigma margin

static __device__ __forceinline__ float bcast_lane(float x, int k) {
    return __int_as_float(__builtin_amdgcn_readlane(__float_as_int(x), k));
}

__global__ void zero_ints(int* __restrict__ p, int n) {
    int i = blockIdx.x * blockDim.x + threadIdx.x;
    if (i < n) p[i] = 0;
}

// x (fp32) -> xh (fp16), pre-scaled by dis[row]: s = dis[n]*x[n]
__global__ void prescale_x(const float* __restrict__ x, const float* __restrict__ dis,
                           __half* __restrict__ out, int n2) {
    int i = blockIdx.x * blockDim.x + threadIdx.x;
    if (i < n2) {
        int n = i >> 5;                 // 32 half2 per row
        float d = dis[n];
        float2 v = ((const float2*)x)[i];
        ((__half2*)out)[i] = __floats2half2_rn(v.x * d, v.y * d);
    }
}

// Bin edges into buckets of 256 consecutive dst nodes. Per-block LDS histogram
// + one bulk atomic reservation per (block,bucket) -> writes to each bucket
// region come from one CU in a tight window (lines fill inside one XCD L2).
__global__ __launch_bounds__(256) void bucket_scatter(const int* __restrict__ src,
                                                      const int* __restrict__ dst, int E,
                                                      int nb, int* __restrict__ gcursor,
                                                      unsigned long long* __restrict__ bpair) {
    __shared__ int lhist[NBMAX];
    __shared__ int lbase[NBMAX];
    int t = threadIdx.x;
    for (int i = t; i < nb; i += 256) lhist[i] = 0;
    __syncthreads();
    int e0 = blockIdx.x * 4096, e1 = min(e0 + 4096, E);
    for (int e = e0 + t; e < e1; e += 256) atomicAdd(&lhist[dst[e] >> 8], 1);
    __syncthreads();
    for (int i = t; i < nb; i += 256) {
        int c = lhist[i];
        lbase[i] = c ? atomicAdd(&gcursor[i], c) : 0;
        lhist[i] = 0;
    }
    __syncthreads();
    for (int e = e0 + t; e < e1; e += 256) {
        int d = dst[e];
        int b = d >> 8;
        int r = lbase[b] + atomicAdd(&lhist[b], 1);
        if (r < BCAP)
            bpair[(long)b * BCAP + r] =
                ((unsigned long long)(unsigned)d << 32) | (unsigned)src[e];
    }
}

// Exclusive scan of nb (<512) bucket counts -> gbase, total at gbase[nb].
__global__ void scan_buckets(const int* __restrict__ gcursor, int B, int* __restrict__ gbase) {
    __shared__ int s[512];
    int t = threadIdx.x;
    s[t] = (t < B) ? gcursor[t] : 0;
    __syncthreads();
    for (int off = 1; off < 512; off <<= 1) {
        int v = (t >= off) ? s[t - off] : 0;
        __syncthreads();
        s[t] += v;
        __syncthreads();
    }
    if (t < B) gbase[t] = (t == 0) ? 0 : s[t - 1];
    if (t == 0) gbase[B] = s[511];
}

// One block per bucket: local histogram + scan in LDS, emit row_ptr/dis
// (coalesced) and adj_src (scatter confined to a ~16KB L2-local window).
__global__ __launch_bounds__(256) void bucket_build(const unsigned long long* __restrict__ bpair,
                                                    int nb, int N,
                                                    const int* __restrict__ gcursor,
                                                    const int* __restrict__ gbase,
                                                    int* __restrict__ row_ptr,
                                                    float* __restrict__ dis,
                                                    int* __restrict__ adj_src) {
    __shared__ int hist[256];
    __shared__ int cur[256];
    __shared__ int wsum[4];
    int b = blockIdx.x, t = threadIdx.x;
    int node_base = b << 8;
    int cnt = gcursor[b];
    if (cnt > BCAP) cnt = BCAP;
    int ebase = gbase[b];
    const unsigned long long* bp = bpair + (long)b * BCAP;

    hist[t] = 0;
    __syncthreads();
    for (int i = t; i < cnt; i += 256) {
        int d = (int)(bp[i] >> 32);
        atomicAdd(&hist[d - node_base], 1);
    }
    __syncthreads();
    int val = hist[t];
    int lane = t & 63, wv = t >> 6;
    int v = val;
#pragma unroll
    for (int off = 1; off < 64; off <<= 1) {
        int u = __shfl_up(v, off, 64);
        if (lane >= off) v += u;
    }
    if (lane == 63) wsum[wv] = v;
    __syncthreads();
    int wo = 0;
#pragma unroll
    for (int w = 0; w < 4; w++)
        if (w < wv) wo += wsum[w];
    int excl = wo + v - val;
    int node = node_base + t;
    if (node < N) {
        row_ptr[node] = ebase + excl;
        dis[node] = rsqrtf((float)(val + 1));  // +1 self-loop
    }
    cur[t] = ebase + excl;
    __syncthreads();
    for (int i = t; i < cnt; i += 256) {
        unsigned long long p = bp[i];
        int d = (int)(p >> 32);
        int pos = atomicAdd(&cur[d - node_base], 1);
        adj_src[pos] = (int)(p & 0xffffffffu);
    }
    if (b == 0 && t == 0) row_ptr[N] = gbase[nb];
}

// Fused GCN layer on pre-scaled storage s[n] = dis[n]*h[n]:
//   y[n] = dis[n] * ( sum_a s[a] + s[n] )       (self-loop included)
//   o    = relu(y @ W + b); store scale_out ? dis[n]*o : o
// Gathers: lane l loads half2 col (l&31) of row a_{2j+(l>=32)} -> one load
// instruction covers TWO rows. adj indices: one batched load per 8 edges,
// extracted per-pair via __shfl (ds_bpermute). No per-edge dis lookups.
__global__ __launch_bounds__(256) void fused_layer(const __half* __restrict__ in,
                                                   const int* __restrict__ row_ptr,
                                                   const int* __restrict__ adj_src,
                                                   const float* __restrict__ dis,
                                                   const float* __restrict__ Wg,
                                                   const float* __restrict__ bias,
                                                   __half* __restrict__ out, int N,
                                                   int total_waves, int scale_out) {
    __shared__ float Wlds[D * D];
#pragma unroll
    for (int r = 0; r < 16; r++) Wlds[r * 256 + threadIdx.x] = Wg[r * 256 + threadIdx.x];
    int lane = threadIdx.x & 63;
    int half_id = lane >> 5;    // which of the 2 rows this lane gathers
    int l31 = lane & 31;        // half2 column within row
    float bl = bias[lane];
    __syncthreads();

    const __half2* in2 = (const __half2*)in;   // row n starts at n*32

    int wave = (blockIdx.x * blockDim.x + threadIdx.x) >> 6;
    for (int n = wave; n < N; n += total_waves) {
        float dn = dis[n];
        int e = row_ptr[n], e_end = row_ptr[n + 1];
        float ax = 0.f, ay = 0.f;

        // main loop: 8 edges per iter = 1 adj load + 4 pair row-loads
        for (; e + 8 <= e_end; e += 8) {
            int av = adj_src[e + (lane & 7)];
#pragma unroll
            for (int j = 0; j < 4; j++) {
                int a = __shfl(av, 2 * j + half_id, 64);
                float2 r = __half22float2(in2[(long)a * 32 + l31]);
                ax += r.x;
                ay += r.y;
            }
        }
        // pair tail
        for (; e + 2 <= e_end; e += 2) {
            int a = adj_src[e + half_id];
            float2 r = __half22float2(in2[(long)a * 32 + l31]);
            ax += r.x;
            ay += r.y;
        }
        // single tail (only half 0 contributes)
        if (e < e_end) {
            int a = adj_src[e];
            if (half_id == 0) {
                float2 r = __half22float2(in2[(long)a * 32 + l31]);
                ax += r.x;
                ay += r.y;
            }
        }
        // combine the two halves: every lane now holds the full edge sum
        ax += __shfl_xor(ax, 32, 64);
        ay += __shfl_xor(ay, 32, 64);

        // self-loop term (s[n]) and final dis[n] scale
        float2 sf = __half22float2(in2[(long)n * 32 + l31]);
        float yx = dn * (ax + sf.x);
        float yy = dn * (ay + sf.y);

        // o[d] = sum_k y[k] * W[k][d] + b[d]; y[2m]=lane m .x, y[2m+1]=lane m .y
        float o = bl;
#pragma unroll
        for (int m = 0; m < 32; m++) {
            o = fmaf(bcast_lane(yx, m), Wlds[(2 * m) * D + lane], o);
            o = fmaf(bcast_lane(yy, m), Wlds[(2 * m + 1) * D + lane], o);
        }
        float res = fmaxf(o, 0.f);
        if (scale_out) res *= dn;       // pre-scale for next layer's gather
        out[(long)n * D + lane] = __float2half(res);
    }
}

// Pool phase 1: grid-chunked over sorted nodes; per-wave run accumulation,
// one atomicAdd per (graph-run, lane) per wave.
__global__ __launch_bounds__(256) void pool_partial(const __half* __restrict__ h,
                                                    const int* __restrict__ batch, int N,
                                                    int chunk, float* __restrict__ pooled) {
    int lane = threadIdx.x & 63;
    int wv = threadIdx.x >> 6;
    int c0 = blockIdx.x * chunk;
    int c1 = min(c0 + chunk, N);
    int g_cur = -1;
    float acc = 0.f;
    for (int n = c0 + wv; n < c1; n += 4) {
        int g = batch[n];
        if (g != g_cur) {
            if (g_cur >= 0) atomicAdd(&pooled[g_cur * D + lane], acc);
            g_cur = g;
            acc = 0.f;
        }
        acc += __half2float(h[n * D + lane]);
    }
    if (g_cur >= 0) atomicAdd(&pooled[g_cur * D + lane], acc);
}

// Pool phase 2: one wave per graph, dot with lin_w.
__global__ void pool_linear(const float* __restrict__ pooled,
                            const float* __restrict__ lin_w,
                            const float* __restrict__ lin_b,
                            float* __restrict__ out, int G) {
    int lane = threadIdx.x & 63;
    int g = blockIdx.x * (blockDim.x >> 6) + (threadIdx.x >> 6);
    if (g >= G) return;
    float t = pooled[g * D + lane] * lin_w[lane];
#pragma unroll
    for (int off = 32; off >= 1; off >>= 1) t += __shfl_down(t, off, 64);
    if (lane == 0) out[g] = t + lin_b[0];
}

extern "C" void kernel_launch(void* const* d_in, const int* in_sizes, int n_in,
                              void* d_out, int out_size, void* d_ws, size_t ws_size,
                              hipStream_t stream) {
    const float* x      = (const float*)d_in[0];
    const int*   edges  = (const int*)d_in[1];
    const int*   batch  = (const int*)d_in[2];
    const float* W1     = (const float*)d_in[3];
    const float* b1     = (const float*)d_in[4];
    const float* W2     = (const float*)d_in[5];
    const float* b2     = (const float*)d_in[6];
    const float* W3     = (const float*)d_in[7];
    const float* b3     = (const float*)d_in[8];
    const float* lin_w  = (const float*)d_in[9];
    const float* lin_b  = (const float*)d_in[10];
    float* out = (float*)d_out;

    const int N = in_sizes[2];        // 100000
    const int E = in_sizes[1] / 2;    // 1600000
    const int G = out_size;           // 64 graphs
    const int nb = (N + 255) >> 8;    // 391 buckets of 256 nodes

    const int* e_src = edges;         // edge_index[0]
    const int* e_dst = edges + E;     // edge_index[1]

    // workspace layout (4B-element offsets, 64-elem aligned)
    auto al = [](long v) { return (v + 63) & ~63L; };
    long o_gcur   = 0;                       // NBMAX ints
    long o_pooled = al(o_gcur + NBMAX);      // G*D floats
    long o_gbase  = al(o_pooled + (long)G * D);
    long o_rowptr = al(o_gbase + nb + 1);
    long o_dis    = al(o_rowptr + N + 1);
    long o_adjs   = al(o_dis + N);
    long o_xh     = al(o_adjs + E);              // N*D halves
    long o_hA     = al(o_xh + (long)N * D / 2);  // aliases bpair (16MB < 25.6MB slot)
    long o_hB     = o_hA + (long)N * D;          // fp32-sized slots used as half buffers

    int*    gcursor = (int*)d_ws + o_gcur;
    float*  pooled  = (float*)d_ws + o_pooled;
    int*    gbase   = (int*)d_ws + o_gbase;
    int*    row_ptr = (int*)d_ws + o_rowptr;
    float*  dis     = (float*)d_ws + o_dis;
    int*    adj_src = (int*)d_ws + o_adjs;
    __half* xh      = (__half*)((float*)d_ws + o_xh);
    __half* hA      = (__half*)((float*)d_ws + o_hA);
    __half* hB      = (__half*)((float*)d_ws + o_hB);
    // bpair (nb*BCAP ulongs = 16 MB) aliases hA slot: dead before layer 2 writes hA.
    unsigned long long* bpair = (unsigned long long*)hA;

    // zero gcursor + pooled (contiguous)
    int nz = (int)(o_pooled + (long)G * D);
    zero_ints<<<(nz + 255) / 256, 256, 0, stream>>>((int*)d_ws, nz);

    // CSR build first (produces dis), then pre-scaled fp16 convert of x
    bucket_scatter<<<(E + 4095) / 4096, 256, 0, stream>>>(e_src, e_dst, E, nb, gcursor, bpair);
    scan_buckets<<<1, 512, 0, stream>>>(gcursor, nb, gbase);
    bucket_build<<<nb, 256, 0, stream>>>(bpair, nb, N, gcursor, gbase, row_ptr, dis, adj_src);

    int n2 = N * D / 2;
    prescale_x<<<(n2 + 255) / 256, 256, 0, stream>>>(x, dis, xh, n2);

    // fused GCN layers: xh -> hB -> hA -> hB
    // layers 1,2 store dis-pre-scaled output; layer 3 stores plain relu for pooling
    const int fl_blocks = 2048;
    const int total_waves = fl_blocks * 4;
    fused_layer<<<fl_blocks, 256, 0, stream>>>(xh, row_ptr, adj_src, dis, W1, b1, hB, N, total_waves, 1);
    fused_layer<<<fl_blocks, 256, 0, stream>>>(hB, row_ptr, adj_src, dis, W2, b2, hA, N, total_waves, 1);
    fused_layer<<<fl_blocks, 256, 0, stream>>>(hA, row_ptr, adj_src, dis, W3, b3, hB, N, total_waves, 0);

    // pool + final linear
    const int pool_blocks = 512;
    const int chunk = (N + pool_blocks - 1) / pool_blocks;
    pool_partial<<<pool_blocks, 256, 0, stream>>>(hB, batch, N, chunk, pooled);
    pool_linear<<<(G + 3) / 4, 256, 0, stream>>>(pooled, lin_w, lin_b, out, G);
}